// Round 3
// baseline (884.433 us; speedup 1.0000x reference)
//
#include <hip/hip_runtime.h>
#include <stdint.h>

// GraphECL loss on MI355X. N=10000, E=330000, IN=512, HID=OUT=256.
// TEMP=0.5, LAM=1e-3, LAMBDA_LOSS=1, BN_EPS=1e-5.

#define TEMP_INV 2.0f
#define LAMC 1.0e-3f
// sqrt(log2(e)/TEMP): folded into bf16 z/q so MFMA acc == exp2 argument
#define SSCALE 1.6986436f

typedef __attribute__((ext_vector_type(8))) __bf16 bf16x8;
typedef __attribute__((ext_vector_type(4))) float f32x4;

__device__ __forceinline__ unsigned short f2bf(float x) {
  union { float f; unsigned int u; } v; v.f = x;
  unsigned int r = v.u + 0x7FFFu + ((v.u >> 16) & 1u);
  return (unsigned short)(r >> 16);
}

__device__ __forceinline__ void g2lds16(const void* gc, void* l) {
  void* g = const_cast<void*>(gc);
  __builtin_amdgcn_global_load_lds(
      (__attribute__((address_space(1))) void*)g,
      (__attribute__((address_space(3))) void*)l, 16, 0, 0);
}

// ---------------- degrees ----------------
__global__ void k_deg(const int* __restrict__ src, const int* __restrict__ dst,
                      float* deg_out, float* deg_in, int E) {
  int i = blockIdx.x * blockDim.x + threadIdx.x;
  if (i < E) {
    atomicAdd(&deg_out[src[i]], 1.0f);
    atomicAdd(&deg_in[dst[i]], 1.0f);
  }
}

__global__ void k_rdeg(const float* __restrict__ deg_out, const float* __restrict__ deg_in,
                       float* rdo, float* rdi, float* idi, int N) {
  int i = blockIdx.x * blockDim.x + threadIdx.x;
  if (i < N) {
    float o = deg_out[i], d = deg_in[i];
    rdo[i] = rsqrtf(o);
    rdi[i] = rsqrtf(d);
    idi[i] = 1.0f / d;  // self loops guarantee d >= 1
  }
}

// exclusive prefix sum of deg_in (ints stored as exact floats); 1 block, 1024 thr
__global__ void k_scan(const float* __restrict__ deg, int* __restrict__ off, int N, int E) {
  __shared__ int sm[1024];
  int tid = threadIdx.x;
  int chunk = (N + 1023) / 1024;
  int b = tid * chunk;
  int sum = 0;
  for (int j = 0; j < chunk; j++) { int i = b + j; if (i < N) sum += (int)deg[i]; }
  sm[tid] = sum;
  __syncthreads();
  for (int s = 1; s < 1024; s <<= 1) {
    int v = (tid >= s) ? sm[tid - s] : 0;
    __syncthreads();
    sm[tid] += v;
    __syncthreads();
  }
  int run = (tid == 0) ? 0 : sm[tid - 1];
  for (int j = 0; j < chunk; j++) {
    int i = b + j;
    if (i < N) { off[i] = run; run += (int)deg[i]; }
  }
  if (tid == 0) off[N] = E;
}

__global__ void k_fill(const int* __restrict__ src, const int* __restrict__ dst,
                       const int* __restrict__ off, int* cur,
                       const float* __restrict__ rdo, const float* __restrict__ rdi,
                       int* adj, float* aw, int E) {
  int e = blockIdx.x * blockDim.x + threadIdx.x;
  if (e < E) {
    int u = src[e], v = dst[e];
    int slot = off[v] + atomicAdd(&cur[v], 1);
    adj[slot] = u;
    aw[slot] = rdo[u] * rdi[v];  // symmetric GCN norm per edge
  }
}

// ---------------- fp32 GEMM: C[M,256] = A[M,K] @ W[K,256] (+bias) ----------------
// 64-row tile, 256 thr, thread = 4 rows x 16 cols (cols 64t+4cg: Wl reads 2-way
// bank-free). At stride 68 floats keeps ds_read_b128 16B-aligned. In-place
// (C==A) safe: each block reads only its own 64 A-rows, stores at the very end.
template <int K, bool BIAS>
__global__ __launch_bounds__(256, 2) void k_gemm(const float* A, const float* __restrict__ W,
                                                 const float* __restrict__ bias, float* C, int M) {
  __shared__ float At[32][68];   // transposed A tile (stride 68: aligned + low conflict)
  __shared__ float Wl[32][256];
  int tid = threadIdx.x;
  int rg = tid >> 4, cg = tid & 15;
  int r0 = rg * 4, cb = cg * 4;
  int row0 = blockIdx.x * 64;
  float acc[4][16] = {};
  for (int k0 = 0; k0 < K; k0 += 32) {
    __syncthreads();
#pragma unroll
    for (int t = 0; t < 2; t++) {
      int lin = tid + 256 * t;            // 0..511
      int r = lin >> 3, k4 = (lin & 7) * 4;
      int ar = row0 + r; if (ar >= M) ar = M - 1;   // tail clamp (rows discarded)
      float4 a4 = *(const float4*)(A + (size_t)ar * K + k0 + k4);
      At[k4 + 0][r] = a4.x; At[k4 + 1][r] = a4.y;
      At[k4 + 2][r] = a4.z; At[k4 + 3][r] = a4.w;
    }
#pragma unroll
    for (int t = 0; t < 8; t++) {
      int lin = tid + 256 * t;            // 0..2047
      int kk = lin >> 6, c4 = (lin & 63) * 4;
      *(float4*)&Wl[kk][c4] = *(const float4*)(W + (size_t)(k0 + kk) * 256 + c4);
    }
    __syncthreads();
#pragma unroll
    for (int k = 0; k < 32; k++) {
      float4 a4 = *(const float4*)&At[k][r0];   // aligned (272B row stride), bcast
      float av[4] = {a4.x, a4.y, a4.z, a4.w};
#pragma unroll
      for (int t = 0; t < 4; t++) {
        float4 w4 = *(const float4*)&Wl[k][64 * t + cb];   // block 16t+cg: 2-way free
#pragma unroll
        for (int i = 0; i < 4; i++) {
          acc[i][4 * t + 0] += av[i] * w4.x;
          acc[i][4 * t + 1] += av[i] * w4.y;
          acc[i][4 * t + 2] += av[i] * w4.z;
          acc[i][4 * t + 3] += av[i] * w4.w;
        }
      }
    }
  }
#pragma unroll
  for (int i = 0; i < 4; i++) {
    int r = row0 + r0 + i;
    if (r < M) {
      float* crow = C + (size_t)r * 256;
#pragma unroll
      for (int t = 0; t < 4; t++) {
        int c = 64 * t + cb;
        float4 v = {acc[i][4 * t], acc[i][4 * t + 1], acc[i][4 * t + 2], acc[i][4 * t + 3]};
        if constexpr (BIAS) {
          float4 b4 = *(const float4*)(bias + c);
          v.x += b4.x; v.y += b4.y; v.z += b4.z; v.w += b4.w;
        }
        *(float4*)(crow + c) = v;
      }
    }
  }
}

// ---- fused dual GEMM (same A, two W): C1 = A@W1, C2 = A@W2 + b2. K=512. ----
__global__ __launch_bounds__(256, 2) void k_gemm2(const float* __restrict__ A,
                                                  const float* __restrict__ W1f,
                                                  const float* __restrict__ W2f,
                                                  const float* __restrict__ b2f,
                                                  float* __restrict__ C1, float* __restrict__ C2,
                                                  int M) {
  __shared__ float At[32][68];
  __shared__ float Wl[2][32][256];
  int tid = threadIdx.x;
  int rg = tid >> 4, cg = tid & 15;
  int r0 = rg * 4, cb = cg * 4;
  int row0 = blockIdx.x * 64;
  float acc1[4][16] = {};
  float acc2[4][16] = {};
  for (int k0 = 0; k0 < 512; k0 += 32) {
    __syncthreads();
#pragma unroll
    for (int t = 0; t < 2; t++) {
      int lin = tid + 256 * t;
      int r = lin >> 3, k4 = (lin & 7) * 4;
      int ar = row0 + r; if (ar >= M) ar = M - 1;
      float4 a4 = *(const float4*)(A + (size_t)ar * 512 + k0 + k4);
      At[k4 + 0][r] = a4.x; At[k4 + 1][r] = a4.y;
      At[k4 + 2][r] = a4.z; At[k4 + 3][r] = a4.w;
    }
#pragma unroll
    for (int t = 0; t < 8; t++) {
      int lin = tid + 256 * t;
      int kk = lin >> 6, c4 = (lin & 63) * 4;
      *(float4*)&Wl[0][kk][c4] = *(const float4*)(W1f + (size_t)(k0 + kk) * 256 + c4);
      *(float4*)&Wl[1][kk][c4] = *(const float4*)(W2f + (size_t)(k0 + kk) * 256 + c4);
    }
    __syncthreads();
#pragma unroll
    for (int k = 0; k < 32; k++) {
      float4 a4 = *(const float4*)&At[k][r0];
      float av[4] = {a4.x, a4.y, a4.z, a4.w};
#pragma unroll
      for (int t = 0; t < 4; t++) {
        float4 w4 = *(const float4*)&Wl[0][k][64 * t + cb];
        float4 u4 = *(const float4*)&Wl[1][k][64 * t + cb];
#pragma unroll
        for (int i = 0; i < 4; i++) {
          acc1[i][4 * t + 0] += av[i] * w4.x; acc1[i][4 * t + 1] += av[i] * w4.y;
          acc1[i][4 * t + 2] += av[i] * w4.z; acc1[i][4 * t + 3] += av[i] * w4.w;
          acc2[i][4 * t + 0] += av[i] * u4.x; acc2[i][4 * t + 1] += av[i] * u4.y;
          acc2[i][4 * t + 2] += av[i] * u4.z; acc2[i][4 * t + 3] += av[i] * u4.w;
        }
      }
    }
  }
#pragma unroll
  for (int i = 0; i < 4; i++) {
    int r = row0 + r0 + i;
    if (r < M) {
#pragma unroll
      for (int t = 0; t < 4; t++) {
        int c = 64 * t + cb;
        float4 v1 = {acc1[i][4 * t], acc1[i][4 * t + 1], acc1[i][4 * t + 2], acc1[i][4 * t + 3]};
        float4 v2 = {acc2[i][4 * t], acc2[i][4 * t + 1], acc2[i][4 * t + 2], acc2[i][4 * t + 3]};
        float4 b4 = *(const float4*)(b2f + c);
        v2.x += b4.x; v2.y += b4.y; v2.z += b4.z; v2.w += b4.w;
        *(float4*)(C1 + (size_t)r * 256 + c) = v1;
        *(float4*)(C2 + (size_t)r * 256 + c) = v2;
      }
    }
  }
}

// ---------------- BatchNorm (train) stats + apply + relu ----------------
__global__ void k_bnstat(const float* __restrict__ T, float* s, float* ss, int M) {
  int c = threadIdx.x;
  int r0 = blockIdx.x * 64;
  float a = 0, b = 0;
  for (int r = r0; r < r0 + 64 && r < M; r++) {
    float v = T[(size_t)r * 256 + c];
    a += v; b += v * v;
  }
  atomicAdd(&s[c], a);
  atomicAdd(&ss[c], b);
}

__global__ void k_bnrelu(float* T, const float* __restrict__ s, const float* __restrict__ ss,
                         const float* __restrict__ g, const float* __restrict__ b, int M) {
  int r = blockIdx.x, c = threadIdx.x;
  float invM = 1.0f / (float)M;
  float mu = s[c] * invM;
  float var = ss[c] * invM - mu * mu;   // biased var, matches jnp.var
  float w = rsqrtf(var + 1e-5f) * g[c];
  float v = T[(size_t)r * 256 + c];
  v = (v - mu) * w + b[c];
  T[(size_t)r * 256 + c] = fmaxf(v, 0.0f);
}

// ---------------- CSR gather-aggregate: Y[v] = sum_{in-edges} w * X[src] (+bias)(relu) ---------
template <bool UNIT, bool RELU>
__global__ __launch_bounds__(256) void k_agg(const float* __restrict__ X, const int* __restrict__ off,
                                             const int* __restrict__ adj, const float* __restrict__ w,
                                             const float* __restrict__ bias, float* __restrict__ Y, int N) {
  int wv = threadIdx.x >> 6, ln = threadIdx.x & 63;
  int v = blockIdx.x * 4 + wv;
  if (v >= N) return;
  int s0 = off[v], s1 = off[v + 1];
  const float4* X4 = (const float4*)X;
  float4 acc = {0, 0, 0, 0};
  for (int s = s0; s < s1; s++) {
    int u = adj[s];
    float wt = UNIT ? 1.0f : w[s];
    float4 x = X4[(size_t)u * 64 + ln];
    acc.x += wt * x.x; acc.y += wt * x.y; acc.z += wt * x.z; acc.w += wt * x.w;
  }
  if constexpr (!UNIT) {
    float4 b = ((const float4*)bias)[ln];
    acc.x += b.x; acc.y += b.y; acc.z += b.z; acc.w += b.w;
  }
  if constexpr (RELU) {
    acc.x = fmaxf(acc.x, 0.f); acc.y = fmaxf(acc.y, 0.f);
    acc.z = fmaxf(acc.z, 0.f); acc.w = fmaxf(acc.w, 0.f);
  }
  ((float4*)Y)[(size_t)v * 64 + ln] = acc;
}

// ---------------- row L2-normalize (in place) + scaled bf16 copy; zero pad rows -----------
__global__ __launch_bounds__(256) void k_norm(float* X, unsigned short* Xb, int N, int NPAD) {
  int wv = threadIdx.x >> 6, ln = threadIdx.x & 63;
  int r = blockIdx.x * 4 + wv;
  if (r >= NPAD) return;
  if (r >= N) {  // exact zeros -> each pad j-row adds exp2(0)=1, corrected in k_final
    ushort4 z = {0, 0, 0, 0};
    ((ushort4*)Xb)[(size_t)r * 64 + ln] = z;
    return;
  }
  float4 x = ((const float4*)X)[(size_t)r * 64 + ln];
  float ss = x.x * x.x + x.y * x.y + x.z * x.z + x.w * x.w;
#pragma unroll
  for (int m = 1; m < 64; m <<= 1) ss += __shfl_xor(ss, m, 64);
  float sc = 1.0f / fmaxf(sqrtf(ss), 1e-12f);
  float4 xn = {x.x * sc, x.y * sc, x.z * sc, x.w * sc};
  ((float4*)X)[(size_t)r * 64 + ln] = xn;
  float bs = sc * SSCALE;
  ushort4 b;
  b.x = f2bf(x.x * bs); b.y = f2bf(x.y * bs);
  b.z = f2bf(x.z * bs); b.w = f2bf(x.w * bs);
  ((ushort4*)Xb)[(size_t)r * 64 + ln] = b;
}

// ---------------- similarity row-sums: S1[i]=sum_j exp(z_i.z_j/T), S2[i]=sum_j exp(z_i.q_j/T) ---
// 256 i-rows/block (4 waves x 64 rows, rf=4 -> 64 FLOP per LDS byte), A-frags
// loaded per-lane from global (once per block). j-tiles of 32 Z + 32 Q rows,
// double-buffered in LDS (2 x 32 KB); STAGE(t+1) issued BEFORE COMPUTE(t) so
// L2/L3 staging latency hides under ~2500 cy of MFMA (T3-minimum pipeline,
// one barrier per tile). XOR swizzle byte^=((row&7)<<4) on global source +
// ds_read address (linear LDS dest), bank-group uniform for all reads.
__global__ __launch_bounds__(256, 2) void k_sim(const unsigned short* __restrict__ Zb,
                                                const unsigned short* __restrict__ Qb,
                                                float* __restrict__ S1, float* __restrict__ S2,
                                                int N, int JT, int JS) {
  __shared__ __align__(1024) char LB[2][32768];
  const int tid = threadIdx.x;
  const int wv = tid >> 6, ln = tid & 63;
  const int i0 = blockIdx.x * 256;
  const int wb = wv * 64;

  auto STAGE = [&](int jt, int b) {
    int j0 = jt * 32;
    char* Lb = (char*)LB[b];
#pragma unroll
    for (int it = 0; it < 8; it++) {
      int c = it * 4 + wv;                 // 1KB chunk = 2 rows
      int L = c * 1024 + ln * 16;
      int r = L >> 9;                      // 0..31 = Z rows, 32..63 = Q rows
      int o = (L & 511) ^ ((r & 7) << 4);
      const char* g = (r < 32) ? (const char*)Zb + (size_t)(j0 + r) * 512 + o
                               : (const char*)Qb + (size_t)(j0 + r - 32) * 512 + o;
      g2lds16(g, Lb + c * 1024);
    }
  };

  int jt0 = (blockIdx.y * JT) / JS;
  int jt1 = ((blockIdx.y + 1) * JT) / JS;

  STAGE(jt0, 0);

  // A fragments from global: wave owns rows i0+wb .. +63 (4 rowfrags), K=256
  bf16x8 af[4][8];
#pragma unroll
  for (int rf = 0; rf < 4; rf++) {
    const char* arow = (const char*)(Zb + (size_t)(i0 + wb + rf * 16 + (ln & 15)) * 256);
#pragma unroll
    for (int kk = 0; kk < 8; kk++)
      af[rf][kk] = *(const bf16x8*)(arow + kk * 64 + ((ln >> 4) << 4));
  }

  f32x4 rs[4][2] = {};  // per-lane row-sum accumulators [rowfrag][mat]

  __syncthreads();      // tile jt0 staged (vmcnt drained at barrier)
  int cur = 0;
  for (int jt = jt0; jt < jt1; jt++) {
    if (jt + 1 < jt1) STAGE(jt + 1, cur ^ 1);   // prefetch overlaps compute
    const char* Lb = (const char*)LB[cur];
#pragma unroll
    for (int m = 0; m < 2; m++) {
      f32x4 acc[4][2] = {};
#pragma unroll
      for (int kk = 0; kk < 8; kk++) {
#pragma unroll
        for (int cf = 0; cf < 2; cf++) {
          int brow = m * 32 + cf * 16 + (ln & 15);
          int o = (kk * 64 + ((ln >> 4) << 4)) ^ ((brow & 7) << 4);
          bf16x8 bb = *(const bf16x8*)(Lb + brow * 512 + o);
#pragma unroll
          for (int rf = 0; rf < 4; rf++)
            acc[rf][cf] = __builtin_amdgcn_mfma_f32_16x16x32_bf16(af[rf][kk], bb, acc[rf][cf], 0, 0, 0);
        }
      }
#pragma unroll
      for (int rf = 0; rf < 4; rf++)
#pragma unroll
        for (int i = 0; i < 4; i++)
          rs[rf][m][i] += exp2f(acc[rf][0][i]) + exp2f(acc[rf][1][i]);
    }
    __syncthreads();    // next tile staged; this tile fully consumed
    cur ^= 1;
  }

  // reduce the 16 lanes (same ln>>4 group) sharing each output row; row=(ln>>4)*4+i
#pragma unroll
  for (int rf = 0; rf < 4; rf++)
#pragma unroll
    for (int m = 0; m < 2; m++)
#pragma unroll
      for (int i = 0; i < 4; i++) {
        float v = rs[rf][m][i];
        v += __shfl_xor(v, 1, 64);
        v += __shfl_xor(v, 2, 64);
        v += __shfl_xor(v, 4, 64);
        v += __shfl_xor(v, 8, 64);
        if ((ln & 15) == 0) {
          int row = i0 + wb + rf * 16 + ((ln >> 4) << 2) + i;
          if (row < N) atomicAdd(((m == 0) ? S1 : S2) + row, v);
        }
      }
}

// ---------------- final loss ----------------
__global__ __launch_bounds__(256) void k_final(const float* __restrict__ zsum, const float* __restrict__ q,
                                               const float* __restrict__ S1, const float* __restrict__ S2,
                                               const int* __restrict__ off, const int* __restrict__ adj,
                                               const float* __restrict__ idi, float* __restrict__ out,
                                               int N, float pad) {
  int wv = threadIdx.x >> 6, ln = threadIdx.x & 63;
  int v = blockIdx.x * 4 + wv;
  if (v >= N) return;
  float4 zs = ((const float4*)zsum)[(size_t)v * 64 + ln];
  float4 qv = ((const float4*)q)[(size_t)v * 64 + ln];
  float d = zs.x * qv.x + zs.y * qv.y + zs.z * qv.z + zs.w * qv.w;
  float s1v = S1[v] - pad;  // remove pad-row exp2(0)=1 contributions
  float lg = 0.0f;
  int e0 = off[v], e1 = off[v + 1];
  for (int s = e0 + ln; s < e1; s += 64) {
    int u = adj[s];
    lg += logf(s1v + LAMC * (S2[u] - pad));
  }
#pragma unroll
  for (int m = 1; m < 64; m <<= 1) {
    d += __shfl_xor(d, m, 64);
    lg += __shfl_xor(lg, m, 64);
  }
  if (ln == 0) {
    float inv = idi[v];
    float posv = d * inv * TEMP_INV;
    float negv = lg * inv;
    atomicAdd(out, (negv - posv) * (1.0f / (float)N));
  }
}

// ---------------- host ----------------
extern "C" void kernel_launch(void* const* d_in, const int* in_sizes, int n_in,
                              void* d_out, int out_size, void* d_ws, size_t ws_size,
                              hipStream_t stream) {
  const float* feat  = (const float*)d_in[0];
  const float* W1    = (const float*)d_in[1];
  const float* b1    = (const float*)d_in[2];
  const float* W2    = (const float*)d_in[3];
  const float* b2    = (const float*)d_in[4];
  const float* Wt1   = (const float*)d_in[5];
  const float* bt1   = (const float*)d_in[6];
  const float* gamma = (const float*)d_in[7];
  const float* beta  = (const float*)d_in[8];
  const float* Wt2   = (const float*)d_in[9];
  const float* bt2   = (const float*)d_in[10];
  const float* Wp    = (const float*)d_in[11];
  const float* bp    = (const float*)d_in[12];
  const int*   src   = (const int*)d_in[13];
  const int*   dst   = (const int*)d_in[14];
  const int N = in_sizes[0] / 512;
  const int E = in_sizes[13];
  const int NTI = (N + 255) / 256, NPAD = NTI * 256, JT = NPAD / 32;
  const int JS = 25;  // grid 40x25 = 1000 blocks ~= 3.9/CU, smooth tail
  const float PADF = (float)(NPAD - N);

  char* p = (char*)d_ws;
  auto alloc = [&](size_t bytes) { char* r = p; p += (bytes + 255) & ~(size_t)255; return r; };
  float* B0 = (float*)alloc((size_t)N * 256 * 4);            // xw1 -> xw2 -> zsum
  float* B1 = (float*)alloc((size_t)N * 256 * 4);            // t -> tr -> trans -> p -> q
  float* B2 = (float*)alloc((size_t)N * 256 * 4);            // h1 -> h2 -> z
  unsigned short* zb = (unsigned short*)alloc((size_t)NPAD * 256 * 2);
  unsigned short* qb = (unsigned short*)alloc((size_t)NPAD * 256 * 2);
  int*   off = (int*)alloc((size_t)(N + 1) * 4);
  int*   adj = (int*)alloc((size_t)E * 4);
  float* aw  = (float*)alloc((size_t)E * 4);
  char*  zblk = p;                                           // region zeroed each launch
  float* deg_out = (float*)alloc((size_t)N * 4);
  float* deg_in  = (float*)alloc((size_t)N * 4);
  int*   cur     = (int*)alloc((size_t)N * 4);
  float* S1 = (float*)alloc((size_t)N * 4);
  float* S2 = (float*)alloc((size_t)N * 4);
  float* bns  = (float*)alloc(256 * 4);
  float* bnss = (float*)alloc(256 * 4);
  size_t zbytes = (size_t)(p - zblk);
  float* rdo = (float*)alloc((size_t)N * 4);
  float* rdi = (float*)alloc((size_t)N * 4);
  float* idi = (float*)alloc((size_t)N * 4);
  (void)ws_size; (void)n_in; (void)out_size;

  hipMemsetAsync(zblk, 0, zbytes, stream);
  hipMemsetAsync(d_out, 0, 4, stream);

  int gE = (E + 255) / 256, gN = (N + 255) / 256, gb = (N + 63) / 64, gw = (N + 3) / 4;
  k_deg<<<gE, 256, 0, stream>>>(src, dst, deg_out, deg_in, E);
  k_rdeg<<<gN, 256, 0, stream>>>(deg_out, deg_in, rdo, rdi, idi, N);
  k_scan<<<1, 1024, 0, stream>>>(deg_in, off, N, E);
  k_fill<<<gE, 256, 0, stream>>>(src, dst, off, cur, rdo, rdi, adj, aw, E);

  // fused: xw1 = feat@W1 ; t = feat@Wt1 + bt1
  k_gemm2<<<gb, 256, 0, stream>>>(feat, W1, Wt1, bt1, B0, B1, N);
  k_bnstat<<<(N + 63) / 64, 256, 0, stream>>>(B1, bns, bnss, N);
  k_bnrelu<<<N, 256, 0, stream>>>(B1, bns, bnss, gamma, beta, N);          // tr (in place)
  k_gemm<256, true ><<<gb, 256, 0, stream>>>(B1, Wt2, bt2, B1, N);         // trans (in place)
  k_gemm<256, true ><<<gb, 256, 0, stream>>>(B1, Wp, bp, B1, N);           // p (in place)

  k_agg<false, true ><<<gw, 256, 0, stream>>>(B0, off, adj, aw, b1, B2, N);  // h1
  k_gemm<256, false><<<gb, 256, 0, stream>>>(B2, W2, nullptr, B0, N);        // xw2
  k_agg<false, false><<<gw, 256, 0, stream>>>(B0, off, adj, aw, b2, B2, N);  // h2

  int gnp = (NPAD + 3) / 4;
  k_norm<<<gnp, 256, 0, stream>>>(B2, zb, N, NPAD);  // z (in place) + zb
  k_norm<<<gnp, 256, 0, stream>>>(B1, qb, N, NPAD);  // q (in place) + qb

  dim3 gs(NTI, JS);
  k_sim<<<gs, 256, 0, stream>>>(zb, qb, S1, S2, N, JT, JS);

  k_agg<true, false><<<gw, 256, 0, stream>>>(B2, off, adj, aw, nullptr, B0, N);  // zsum
  k_final<<<gw, 256, 0, stream>>>(B0, B1, S1, S2, off, adj, idi, (float*)d_out, N, PADF);
}